// Round 15
// baseline (181.054 us; speedup 1.0000x reference)
//
#include <hip/hip_runtime.h>

// ---------------------------------------------------------------------------
// ConvCaps (EM routing): b=8, B=32, C=32, K=3, stride=2, Win=13, Wout=6, 3 iters
// x: (8, 544, 13, 13) f32   [pose 512ch = (q,r,o), act 32ch]
// W: (3,3,32,32,4,4) f32    [ch=(ij*32+o)][c][p][q], 512 floats per ch
// out: (8, 544, 6, 6) f32
// vote[d=p*4+r] = sum_q W[ch][c][p][q] * pose[n,q,r,o, 2x+i, 2y+j]
//
// R25: TRANSPOSED PARALLELIZATION. lane = c (32 c's across lanes), ch
// sequential per thread. One block per sg (512 thr, 16 ch-groups x 18 ch).
//  - (sg,c) accumulation is lane-LOCAL: the 288-way cross-lane reduction
//    (33 wsum64 = ~250 dependent DPP+readlane) is replaced by in-register
//    accumulation + 1 shfl_xor(32) half-combine + small 2-stage LDS reduce.
//  - W relaid [ch][d][c]: loads 2-4 lines/instr (c-contiguous).
//  - P reads become LDS broadcasts (addr uniform per half) - conflict-free.
//  - mu/sigma/log/out parallelize over (c,d)=512 threads (was serial/lane).
//  - staging redundancy 8x down (grid 288 vs 2304); D-atomics 8x down.
//  - p_hat relaid [sg][slot][c] (c-contiguous for both M-read and E-write).
// Evidence: R24 (10% VALU cut) neutral + R23 (arrangement-insensitive) +
// issue-floor arithmetic (7.5us vs 40us measured = 80% stall) point at the
// reduction phases + wave-wide access structure as the remaining cost.
// MODE2 writes out fully parallel. E recomputes votes (no vo cache needed).
// Session rules: spin/coop BANNED. No launch_bounds occupancy arg = VGPR
// cap 256 = spill-impossible. Spill symptom: WRITE_SIZE x20.
// ---------------------------------------------------------------------------

typedef float v2f __attribute__((ext_vector_type(2)));
typedef float v4f __attribute__((ext_vector_type(4)));

// workspace layout (floats)
#define OFF_PHAT 0           // 288*288*32 = 2654208   [sg][slot][c]
#define OFF_D0   2654208     // 43264 = 8*169*32   [n][pix][o]
#define OFF_D1   2697472     // 43264
#define OFF_POST 2740736     // 692224 = 8*32*169*16   [(n,o)][pix][d]
#define OFF_ACTT 3432960     // 43264  [n][pix][o]
#define OFF_WT4  3476224     // 147456 = 288*16*32  [ch][d][c]
// total 3623680 floats = 14.5 MB

__device__ __forceinline__ v2f lo2(v4f a) { return __builtin_shufflevector(a, a, 0, 1); }
__device__ __forceinline__ v2f hi2(v4f a) { return __builtin_shufflevector(a, a, 2, 3); }

// kperm slot table: ij=(i*3+j) -> (i2*3+j2), i2=(3-i)%3, j2=(3-j)%3.
__device__ __constant__ int kp_c[9] = {0, 2, 1, 6, 8, 7, 3, 5, 4};

// One fused prep kernel (range-branched elementwise), 3787*256 = 969472:
//   [0,692224)        pose transpose -> posT[((n*32+o)*169+pix)*16 + d]
//   [692224,735488)   act transpose  -> actT[n][pix][o]
//   [735488,882944)   W relayout     -> Wt4[(ch*16+d)*32 + c]
//   [882944,969472)   zero D0 and D1
__global__ __launch_bounds__(256) void prep_kernel(
    const float* __restrict__ x, const float* __restrict__ Wt,
    float* __restrict__ posT, float* __restrict__ actT,
    float* __restrict__ Wt4, float* __restrict__ Dz) {
  int tid = blockIdx.x * 256 + threadIdx.x;
  if (tid < 692224) {
    int pix = tid % 169; int t = tid / 169;
    int o = t & 31; t >>= 5;
    int d = t & 15; int n = t >> 4;
    float v = x[((size_t)n * 544 + d * 32 + o) * 169 + pix];
    posT[((size_t)(n * 32 + o) * 169 + pix) * 16 + d] = v;
  } else if (tid < 735488) {
    int r = tid - 692224;
    int pix = r % 169; int t = r / 169;
    int o = t & 31; int n = t >> 5;
    float v = x[(size_t)n * 91936 + 86528 + o * 169 + pix];
    actT[((size_t)n * 169 + pix) * 32 + o] = v;
  } else if (tid < 882944) {
    int r = tid - 735488;                 // 147456 = 288*16*32
    int c = r & 31;
    int d = (r >> 5) & 15;
    int ch = r >> 9;                      // 0..287
    Wt4[r] = Wt[(size_t)ch * 512 + c * 16 + d];
  } else {
    Dz[tid - 882944] = 0.f;               // D0 then D1 (contiguous)
  }
}

// Fused EM step, transposed parallelization. Grid 288 (one block per sg),
// 512 threads: c = tid&31, grp = tid>>5 (16 groups x 18 ch).
// MODE 0: M(uniform Rp) + E -> p_hat, Dwrite
// MODE 1: M(p_hat, Dread) + E -> p_hat, Dwrite
// MODE 2: M(p_hat, Dread) -> final output
template <int MODE>
__global__ __launch_bounds__(512) void em_kernel(
    const float* __restrict__ Wt4, const float* __restrict__ posT,
    const float* __restrict__ actT, float* __restrict__ p_hat,
    const float* __restrict__ Dread, float* __restrict__ Dwrite,
    const float* __restrict__ beta_v, const float* __restrict__ beta_a,
    const float* __restrict__ lambda_, float* __restrict__ out) {
  __shared__ float sP[288 * 16];        // pose patch (broadcast reads)
  __shared__ float sE[288];             // a/1152 or a/D per child slot
  __shared__ float sRed[8 * 32 * 37];   // [wave][c][37]: 0=sumr 1+d=sv 17+d=sq
  __shared__ float sMu[32 * 20];        // mu[c][d], padded 20 for v4f reads
  __shared__ float sL[32 * 17];         // log sigma partials
  __shared__ float sG[32];              // per-c G for E

  const int tid = threadIdx.x;
  const int c = tid & 31;
  const int grp = tid >> 5;             // 0..15, ch in [grp*18, grp*18+18)
  const int wv = tid >> 6;              // wave 0..7
  const int sg = blockIdx.x;            // spatial 0..287

  int t = sg;
  const int y = t % 6; t /= 6;
  const int xx = t % 6;
  const int n = t / 6;

  const float bvv = beta_v[0], bav = beta_a[0], lamv = lambda_[0];

  // ---- stage pose patch (coalesced v4f; reads later are broadcasts) ----
  for (int task = tid; task < 1152; task += 512) {
    int ch = task >> 2, q = task & 3;
    int o = ch & 31, ij = ch >> 5;
    int i = ij / 3, j = ij - i * 3;
    int pix = (2 * xx + i) * 13 + (2 * y + j);
    v4f v = *(const v4f*)(posT +
        ((size_t)((n * 32 + o) * 169) + pix) * 16 + q * 4);
    *(v4f*)(sP + ch * 16 + q * 4) = v;
  }
  // ---- stage rhat scale: a/1152 or a/D ----
  for (int task = tid; task < 288; task += 512) {
    int o = task & 31, ij = task >> 5;
    int i = ij / 3, j = ij - i * 3;
    int idx = ((size_t)n * 169 + (2 * xx + i) * 13 + (2 * y + j)) * 32 + o;
    float a = actT[idx];
    sE[task] = (MODE == 0) ? a * (1.0f / 1152.0f) : a / Dread[idx];
  }
  __syncthreads();

  // ---- M step: lane-local accumulation over this thread's 18 ch ----
  float sum_r = 0.f;
  v2f sv2[8], sq2[8];
#pragma unroll
  for (int d = 0; d < 8; ++d) { sv2[d] = 0.f; sq2[d] = 0.f; }

  const int ch0 = grp * 18;
#pragma unroll 2
  for (int ch = ch0; ch < ch0 + 18; ++ch) {
    const float* wp = Wt4 + (size_t)ch * 512 + c;    // [d*32] strided
    float w[16];
#pragma unroll
    for (int d = 0; d < 16; ++d) w[d] = wp[d * 32];
    const v4f* Pp = (const v4f*)(sP + ch * 16);      // broadcast per half
    v4f Pq0 = Pp[0], Pq1 = Pp[1], Pq2 = Pp[2], Pq3 = Pp[3];

    float rhat = sE[ch];
    if (MODE != 0) rhat *= p_hat[((size_t)sg * 288 + ch) * 32 + c];
    sum_r += rhat;

#pragma unroll
    for (int p = 0; p < 4; ++p) {
      v4f vote = w[p * 4 + 0] * Pq0 + w[p * 4 + 1] * Pq1 +
                 w[p * 4 + 2] * Pq2 + w[p * 4 + 3] * Pq3;
      v2f vl = lo2(vote), vh = hi2(vote);
      v2f tl = rhat * vl, th = rhat * vh;
      sv2[2 * p] += tl;     sv2[2 * p + 1] += th;
      sq2[2 * p] += tl * vl; sq2[2 * p + 1] += th * vh;
    }
  }

  // ---- combine the wave's two halves (same c, different grp) ----
  sum_r += __shfl_xor(sum_r, 32);
#pragma unroll
  for (int i = 0; i < 8; ++i) {
    sv2[i].x += __shfl_xor(sv2[i].x, 32);
    sv2[i].y += __shfl_xor(sv2[i].y, 32);
    sq2[i].x += __shfl_xor(sq2[i].x, 32);
    sq2[i].y += __shfl_xor(sq2[i].y, 32);
  }
  if ((tid & 63) < 32) {
    float* r = sRed + (wv * 32 + c) * 37;
    r[0] = sum_r;
#pragma unroll
    for (int d = 0; d < 16; ++d) {
      r[1 + d] = sv2[d >> 1][d & 1];
      r[17 + d] = sq2[d >> 1][d & 1];
    }
  }
  __syncthreads();

  // ---- stage 2: thread (c, d=grp) reduces 8 wave-partials for dim d ----
  const int d = grp;
  float S = 0.f, svd = 0.f, sqd = 0.f;
#pragma unroll
  for (int g = 0; g < 8; ++g) {
    const float* r = sRed + (g * 32 + c) * 37;
    S += r[0]; svd += r[1 + d]; sqd += r[17 + d];
  }
  const float inv_sr = 1.0f / S;
  const float m = svd * inv_sr;
  const float sg_ = fmaxf(sqd * inv_sr - m * m, 1e-30f);
  sMu[c * 20 + d] = m;
  sL[c * 17 + d] = __logf(sg_);
  __syncthreads();

  if (grp == 0) {
    float ls = 0.f;
#pragma unroll
    for (int dd = 0; dd < 16; ++dd) ls += sL[c * 17 + dd];
    const float cost = (16.f * bvv + ls) * S;
    const float aout = 1.0f / (1.0f + __expf(-lamv * (bav - cost)));
    if (MODE == 2) {
      out[(size_t)(n * 544 + 512 + c) * 36 + xx * 6 + y] = aout;
    } else {
      sG[c] = __logf(aout) - 0.5f * (ls + 16.f * 1.8378770664093453f);
    }
  }
  if (MODE == 2) {
    // (c,d) thread writes its mu component; fully parallel output.
    out[(size_t)(n * 544 + c * 16 + d) * 36 + xx * 6 + y] = m;
    return;
  }
  __syncthreads();
  const float G = sG[c];
  const v4f* mup = (const v4f*)(sMu + c * 20);
  v4f mu0 = mup[0], mu1 = mup[1], mu2v = mup[2], mu3 = mup[3];

  // ---- E step: recompute votes per ch (lane-local), store kperm'd ----
#pragma unroll 2
  for (int ch = ch0; ch < ch0 + 18; ++ch) {
    const float* wp = Wt4 + (size_t)ch * 512 + c;
    float w[16];
#pragma unroll
    for (int dd = 0; dd < 16; ++dd) w[dd] = wp[dd * 32];
    const v4f* Pp = (const v4f*)(sP + ch * 16);
    v4f Pq0 = Pp[0], Pq1 = Pp[1], Pq2 = Pp[2], Pq3 = Pp[3];

    v4f ssa = 0.f;
#pragma unroll
    for (int p = 0; p < 4; ++p) {
      v4f vote = w[p * 4 + 0] * Pq0 + w[p * 4 + 1] * Pq1 +
                 w[p * 4 + 2] * Pq2 + w[p * 4 + 3] * Pq3;
      v4f mu_p = (p == 0) ? mu0 : (p == 1) ? mu1 : (p == 2) ? mu2v : mu3;
      v4f dif = vote - mu_p;
      ssa += dif * dif;
    }
    float ss = ssa.x + ssa.y + ssa.z + ssa.w;
    float ph = __expf(G - ss);
    int slot = kp_c[ch >> 5] * 32 + (ch & 31);
    p_hat[((size_t)sg * 288 + slot) * 32 + c] = ph;
  }
  __syncthreads();   // drain p_hat stores (vmcnt) before read-back

  // ---- D reduce: slot-thread sums 32 c (L1/L2 read-back) + atomic ----
  if (tid < 288) {
    const float* pb = p_hat + ((size_t)sg * 288 + tid) * 32;
    v4f a0 = 0.f;
#pragma unroll
    for (int q = 0; q < 8; ++q) a0 += ((const v4f*)pb)[q];
    float s = a0.x + a0.y + a0.z + a0.w;
    int o = tid & 31, ij = tid >> 5;
    int i = ij / 3, j = ij - i * 3;
    atomicAdd(Dwrite + ((size_t)n * 169 + (2 * xx + i) * 13 + (2 * y + j)) * 32 + o, s);
  }
}

extern "C" void kernel_launch(void* const* d_in, const int* in_sizes, int n_in,
                              void* d_out, int out_size, void* d_ws,
                              size_t ws_size, hipStream_t stream) {
  const float* x   = (const float*)d_in[0];
  const float* Wt  = (const float*)d_in[1];
  const float* bv  = (const float*)d_in[2];
  const float* ba  = (const float*)d_in[3];
  const float* lam = (const float*)d_in[4];
  float* out = (float*)d_out;
  float* ws = (float*)d_ws;

  float* p_hat = ws + OFF_PHAT;
  float* D0    = ws + OFF_D0;
  float* D1    = ws + OFF_D1;
  float* posT  = ws + OFF_POST;
  float* actT  = ws + OFF_ACTT;
  float* Wt4   = ws + OFF_WT4;

  (void)in_sizes; (void)n_in; (void)out_size; (void)ws_size;

  // fused prep: transposes + W relayout + zero D0/D1
  prep_kernel<<<3787, 256, 0, stream>>>(x, Wt, posT, actT, Wt4, D0);

  // M0 + E1 -> p_hat, D0
  em_kernel<0><<<288, 512, 0, stream>>>(Wt4, posT, actT, p_hat, D1, D0,
                                        bv, ba, lam, out);
  // M1 (p_hat, D0) + E2 -> p_hat, D1
  em_kernel<1><<<288, 512, 0, stream>>>(Wt4, posT, actT, p_hat, D0, D1,
                                        bv, ba, lam, out);
  // M2 (p_hat, D1) -> out
  em_kernel<2><<<288, 512, 0, stream>>>(Wt4, posT, actT, p_hat, D1, D0,
                                        bv, ba, lam, out);
}

// Round 16
// 137.490 us; speedup vs baseline: 1.3169x; 1.3169x over previous
//
#include <hip/hip_runtime.h>

// ---------------------------------------------------------------------------
// ConvCaps (EM routing): b=8, B=32, C=32, K=3, stride=2, Win=13, Wout=6, 3 iters
// x: (8, 544, 13, 13) f32   [pose 512ch = (q,r,o), act 32ch]
// W: (3,3,32,32,4,4) f32    [ch=(ij*32+o)][c][p][q], 512 floats per ch
// out: (8, 544, 6, 6) f32
// vote[d=p*4+r] = sum_q W[ch][c][p][q] * pose[n,q,r,o, 2x+i, 2y+j]
//
// R26 = REVERT to R21 (best measured: 136.28us). 3-launch, grid 2304,
// 256thr/4-wave, sP LDS staging, DPP reductions, TA-coalesced Wt3, VGPR
// vote cache. No new experiment.
// R25 post-mortem: transposed (lane=c) structure starved the machine (grid
// 288 ~ 1.1 blk/CU at 62KB LDS; occupancy 11%); per-resident-wave VALU issue
// was actually BETTER than this structure -> per-wave efficiency wasn't the
// remaining cost, grid supply was. Fixing it re-adds cross-block reduction.
// Session ledger: wins = per-wave work deletion only (R11 DPP -14, R20
// W-coalesce -12, R21 vote cache -7). Neutral: R13 TLP, R22 XCD swizzle,
// R24 VALU micro-cuts. Negative: R15 ILP, R19 global-P, R23 grid-halve,
// R25 transpose. Banned by harness: coop launch, spin barriers (R16-18).
// em pinned ~40us with all pipes <20% across every arrangement -> floor is
// structural (4 graph nodes + latency-bound EM core), not a pipe roofline.
// Session rules: launch-bounds arg2 = blocks/CU; NO arg = cap 256 =
// spill-impossible. Spill symptom: WRITE_SIZE x20 (R12/R14).
// p_hat block-private; only D crosses blocks -> ping-pong D0/D1.
// ---------------------------------------------------------------------------

typedef float v2f __attribute__((ext_vector_type(2)));
typedef float v4f __attribute__((ext_vector_type(4)));

// workspace layout (floats)
#define OFF_PHAT 0           // 288*32*288 = 2654208   [spatial][c][slot]
#define OFF_D0   2654208     // 43264 = 8*169*32   [n][pix][o]
#define OFF_D1   2697472     // 43264
#define OFF_POST 2740736     // 692224 = 8*32*169*16   [(n,o)][pix][d]
#define OFF_ACTT 3432960     // 43264  [n][pix][o]
#define OFF_WT3  3476224     // 163840 = 32*5*4*256  [c][k][q][lane][4]
// total 3640064 floats = 14.6 MB

// DPP butterfly-reduce on the VALU pipe (no DS-pipe traffic).
template <int CTRL>
__device__ __forceinline__ float dppadd(float v) {
  int p = __builtin_amdgcn_update_dpp(0, __float_as_int(v), CTRL, 0xF, 0xF, true);
  return v + __int_as_float(p);
}

__device__ __forceinline__ float wsum64(float v) {
  v = dppadd<0xB1>(v);    // quad_perm {1,0,3,2}  : xor 1
  v = dppadd<0x4E>(v);    // quad_perm {2,3,0,1}  : xor 2
  v = dppadd<0x141>(v);   // row_half_mirror      : xor 7  -> 8-lane sums
  v = dppadd<0x140>(v);   // row_mirror           : xor 15 -> row (16) sums
  v = dppadd<0x142>(v);   // row_bcast15: row1 += row0, row3 += row2
  v = dppadd<0x143>(v);   // row_bcast31: rows 2,3 += (row0+row1); lane63 = total
  return __int_as_float(__builtin_amdgcn_readlane(__float_as_int(v), 63));
}

__device__ __forceinline__ v2f lo2(v4f a) { return __builtin_shufflevector(a, a, 0, 1); }
__device__ __forceinline__ v2f hi2(v4f a) { return __builtin_shufflevector(a, a, 2, 3); }

// One fused prep kernel (range-branched elementwise), 3851*256 = 985856:
//   [0,692224)        pose transpose -> posT[((n*32+o)*169+pix)*16 + d]
//   [692224,735488)   act transpose  -> actT[n][pix][o]
//   [735488,899328)   W coalesced    -> Wt3[((c*5+k)*4+q)*256 + lane*4 + j]
//   [899328,985856)   zero D0 and D1
__global__ __launch_bounds__(256) void prep_kernel(
    const float* __restrict__ x, const float* __restrict__ Wt,
    float* __restrict__ posT, float* __restrict__ actT,
    float* __restrict__ Wt3, float* __restrict__ Dz) {
  int tid = blockIdx.x * 256 + threadIdx.x;
  if (tid < 692224) {
    int pix = tid % 169; int t = tid / 169;
    int o = t & 31; t >>= 5;
    int d = t & 15; int n = t >> 4;
    float v = x[((size_t)n * 544 + d * 32 + o) * 169 + pix];
    posT[((size_t)(n * 32 + o) * 169 + pix) * 16 + d] = v;
  } else if (tid < 735488) {
    int r = tid - 692224;
    int pix = r % 169; int t = r / 169;
    int o = t & 31; int n = t >> 5;
    float v = x[(size_t)n * 91936 + 86528 + o * 169 + pix];
    actT[((size_t)n * 169 + pix) * 32 + o] = v;
  } else if (tid < 899328) {
    int r = tid - 735488;                     // 163840 = 32*5*4*256
    int j = r & 3;
    int lane = (r >> 2) & 63;
    int q = (r >> 8) & 3;
    int rem = r >> 10;                        // c*5 + k
    int k = rem % 5; int c = rem / 5;
    int ch = 64 * k + lane;
    Wt3[r] = (ch < 288) ? Wt[(size_t)ch * 512 + c * 16 + 4 * q + j] : 0.f;
  } else {
    Dz[tid - 899328] = 0.f;                   // D0 then D1 (contiguous)
  }
}

// Fused EM step, mode as template (DCE per phase).
// MODE 0: M(uniform Rp) + E -> p_hat, Dwrite
// MODE 1: M(p_hat, Dread) + E -> p_hat, Dwrite
// MODE 2: M(p_hat, Dread) -> final output
template <int MODE>
__global__ __launch_bounds__(256) void em_kernel(
    const float* __restrict__ Wt3, const float* __restrict__ posT,
    const float* __restrict__ actT, float* __restrict__ p_hat,
    const float* __restrict__ Dread, float* __restrict__ Dwrite,
    const float* __restrict__ beta_v, const float* __restrict__ beta_a,
    const float* __restrict__ lambda_, float* __restrict__ out) {
  __shared__ float sP[288 * 20];   // pose patch, stride 20 (float4-aligned)
  __shared__ float sE[288];        // a/1152 or a/D per child slot
  __shared__ float sPh[4 * 288];   // per-wave p_hat by slot, for D reduce

  const int g = blockIdx.x & 7;        // c group
  const int sg = blockIdx.x >> 3;      // spatial 0..287
  const int wave = threadIdx.x >> 6;
  const int lane = threadIdx.x & 63;
  const int c = g * 4 + wave;

  int t = sg;
  const int y = t % 6; t /= 6;
  const int xx = t % 6;
  const int n = t / 6;

  const float bvv = beta_v[0], bav = beta_a[0], lamv = lambda_[0];
  const float* wbase = Wt3 + (size_t)c * 5120;   // [k][q][lane][4]

  // ---- prefetch p_hat (global, coalesced) so vmcnt overlaps staging ----
  float phv[5];
  if (MODE != 0) {
    const float* phb = p_hat + ((size_t)sg * 32 + c) * 288;
#pragma unroll
    for (int k = 0; k < 5; ++k) {
      int ch = lane + 64 * k; if (ch > 287) ch = 287;
      phv[k] = phb[ch];
    }
  }

  // ---- stage pose patch (coalesced float4) ----
  for (int task = threadIdx.x; task < 1152; task += 256) {
    int ch = task >> 2, q = task & 3;
    int o = ch & 31, ij = ch >> 5;
    int i = ij / 3, j = ij - i * 3;
    int pix = (2 * xx + i) * 13 + (2 * y + j);
    v4f v = *(const v4f*)(posT +
        ((size_t)((n * 32 + o) * 169) + pix) * 16 + q * 4);
    *(v4f*)(sP + ch * 20 + q * 4) = v;
  }
  // ---- stage rhat scale: a/1152 or a/D (32-contiguous reads) ----
  for (int task = threadIdx.x; task < 288; task += 256) {
    int o = task & 31, ij = task >> 5;
    int i = ij / 3, j = ij - i * 3;
    int idx = ((size_t)n * 169 + (2 * xx + i) * 13 + (2 * y + j)) * 32 + o;
    float a = actT[idx];
    sE[task] = (MODE == 0) ? a * (1.0f / 1152.0f) : a / Dread[idx];
  }
  __syncthreads();

  // ---- M step: packed float2 accumulation; votes cached in VGPR ----
  float sum_r = 0.f;
  v2f sv2[8], sq2[8];
  v2f vo[40];   // [k][p*2+half] votes, static-indexed after unroll (80 VGPR)
#pragma unroll
  for (int d = 0; d < 8; ++d) { sv2[d] = 0.f; sq2[d] = 0.f; }

#pragma unroll
  for (int k = 0; k < 5; ++k) {
    int ch = lane + 64 * k;
    const bool act_l = (ch < 288);
    const int chm = act_l ? ch : 0;

    const v4f* Pp = (const v4f*)(sP + chm * 20);
    v4f P0 = Pp[0], P1 = Pp[1], P2 = Pp[2], P3 = Pp[3];
    const v4f* Wq = (const v4f*)(wbase + k * 1024);   // 256 v4f per k
    v4f W0 = Wq[lane], W1 = Wq[64 + lane], W2 = Wq[128 + lane], W3 = Wq[192 + lane];

    float rhat = sE[chm];
    if (MODE != 0) rhat *= phv[k];
    if (!act_l) rhat = 0.f;
    sum_r += rhat;

    v2f PL0 = lo2(P0), PH0 = hi2(P0), PL1 = lo2(P1), PH1 = hi2(P1);
    v2f PL2 = lo2(P2), PH2 = hi2(P2), PL3 = lo2(P3), PH3 = hi2(P3);
    v2f r2 = rhat;

#pragma unroll
    for (int p = 0; p < 4; ++p) {
      v4f Wr = (p == 0) ? W0 : (p == 1) ? W1 : (p == 2) ? W2 : W3;
      v2f vlo = Wr.x * PL0 + Wr.y * PL1 + Wr.z * PL2 + Wr.w * PL3;
      v2f vhi = Wr.x * PH0 + Wr.y * PH1 + Wr.z * PH2 + Wr.w * PH3;
      vo[k * 8 + p * 2 + 0] = vlo;
      vo[k * 8 + p * 2 + 1] = vhi;
      v2f tlo = r2 * vlo, thi = r2 * vhi;
      sv2[p * 2 + 0] += tlo;
      sv2[p * 2 + 1] += thi;
      sq2[p * 2 + 0] += tlo * vlo;
      sq2[p * 2 + 1] += thi * vhi;
    }
  }

  sum_r = wsum64(sum_r);
  const float inv_sr = 1.0f / sum_r;
  float mu[16];
  float lsum = 0.f;
  float prod = 1.f;
#pragma unroll
  for (int d = 0; d < 16; ++d) {
    float s1 = wsum64(sv2[d >> 1][d & 1]);
    float s2 = wsum64(sq2[d >> 1][d & 1]);
    float m = s1 * inv_sr;
    mu[d] = m;
    float sg_ = fmaxf(s2 * inv_sr - m * m, 1e-30f);
    prod *= sg_;
    if ((d & 3) == 3) { lsum += __logf(prod); prod = 1.f; }
  }
  const float cost = (16.f * bvv + lsum) * sum_r;
  const float aout = 1.0f / (1.0f + __expf(-lamv * (bav - cost)));

  if (MODE == 2) {
    if (lane == 0) {
      float* ob = out + (size_t)(n * 544 + c * 16) * 36 + xx * 6 + y;
#pragma unroll
      for (int d = 0; d < 16; ++d) ob[d * 36] = mu[d];
      out[(size_t)(n * 544 + 512 + c) * 36 + xx * 6 + y] = aout;
    }
    return;
  }

  // ---- E step: pure register math on cached votes, store kperm'd ----
  v2f mu2[8];
#pragma unroll
  for (int d = 0; d < 8; ++d) { mu2[d].x = mu[2 * d]; mu2[d].y = mu[2 * d + 1]; }
  const float G = __logf(aout) - 0.5f * (lsum + 16.f * 1.8378770664093453f);

#pragma unroll
  for (int k = 0; k < 5; ++k) {
    int mch = lane + 64 * k;
    if (mch < 288) {
      v2f ss2 = 0.f;
#pragma unroll
      for (int p = 0; p < 4; ++p) {
        v2f dlo = vo[k * 8 + p * 2 + 0] - mu2[p * 2 + 0];
        v2f dhi = vo[k * 8 + p * 2 + 1] - mu2[p * 2 + 1];
        ss2 += dlo * dlo;
        ss2 += dhi * dhi;
      }
      float ss = ss2.x + ss2.y;
      float ph = __expf(G - ss);
      int o = mch & 31, ijm = mch >> 5;
      int im = ijm / 3, jm = ijm - im * 3;
      int i2 = (im == 0) ? 0 : 3 - im;   // kperm = {0,2,1}, involution
      int j2 = (jm == 0) ? 0 : 3 - jm;
      int slot = (i2 * 3 + j2) * 32 + o;
      p_hat[((size_t)sg * 32 + c) * 288 + slot] = ph;
      sPh[wave * 288 + slot] = ph;
    }
  }
  __syncthreads();
  // D reduce over block's 4 c + global atomic (8 c-grp blocks contribute)
  for (int t2 = threadIdx.x; t2 < 288; t2 += 256) {
    float s = sPh[t2] + sPh[288 + t2] + sPh[576 + t2] + sPh[864 + t2];
    int o = t2 & 31, ij = t2 >> 5;
    int i = ij / 3, j = ij - i * 3;
    atomicAdd(Dwrite + ((size_t)n * 169 + (2 * xx + i) * 13 + (2 * y + j)) * 32 + o, s);
  }
}

extern "C" void kernel_launch(void* const* d_in, const int* in_sizes, int n_in,
                              void* d_out, int out_size, void* d_ws,
                              size_t ws_size, hipStream_t stream) {
  const float* x   = (const float*)d_in[0];
  const float* Wt  = (const float*)d_in[1];
  const float* bv  = (const float*)d_in[2];
  const float* ba  = (const float*)d_in[3];
  const float* lam = (const float*)d_in[4];
  float* out = (float*)d_out;
  float* ws = (float*)d_ws;

  float* p_hat = ws + OFF_PHAT;
  float* D0    = ws + OFF_D0;
  float* D1    = ws + OFF_D1;
  float* posT  = ws + OFF_POST;
  float* actT  = ws + OFF_ACTT;
  float* Wt3   = ws + OFF_WT3;

  (void)in_sizes; (void)n_in; (void)out_size; (void)ws_size;

  // fused prep: transposes + coalesced W + zero D0/D1
  prep_kernel<<<3851, 256, 0, stream>>>(x, Wt, posT, actT, Wt3, D0);

  // M0 + E1 -> p_hat, D0
  em_kernel<0><<<2304, 256, 0, stream>>>(Wt3, posT, actT, p_hat, D1, D0,
                                         bv, ba, lam, out);
  // M1 (p_hat, D0) + E2 -> p_hat, D1
  em_kernel<1><<<2304, 256, 0, stream>>>(Wt3, posT, actT, p_hat, D0, D1,
                                         bv, ba, lam, out);
  // M2 (p_hat, D1) -> out
  em_kernel<2><<<2304, 256, 0, stream>>>(Wt3, posT, actT, p_hat, D1, D0,
                                         bv, ba, lam, out);
}